// Round 1
// 636.440 us; speedup vs baseline: 1.0302x; 1.0302x over previous
//
#include <hip/hip_runtime.h>
#include <math.h>

#define TT 250
#define BT 256
#define HN 128
#define ON 20
#define KIN 700
#define NKT 22

// ws layout (float offsets): xin[250*256*128] | packed W hi | packed W lo
#define XIN_OFF 0
#define WPKH_OFF 8192000   // 45056 floats (90112 bf16)
#define WPKL_OFF 8237056   // 45056 floats

typedef __attribute__((ext_vector_type(8))) short bf16x8;
typedef __attribute__((ext_vector_type(4))) float f32x4;

__device__ __forceinline__ unsigned short bf16rne(float f) {
    unsigned u = __float_as_uint(f);
    unsigned r = u + 0x7fffu + ((u >> 16) & 1u);
    return (unsigned short)(r >> 16);
}
__device__ __forceinline__ void hilo(float v, short& h, short& l) {
    unsigned short hh = bf16rne(v);
    float vh = __uint_as_float((unsigned)hh << 16);
    h = (short)hh;
    l = (short)bf16rne(v - vh);
}

// lgkm-only barrier: LDS writes visible across waves WITHOUT draining vmcnt,
// so cross-step global prefetch loads stay in flight (guide §5 8-phase pattern).
#define LBAR() do { asm volatile("s_waitcnt lgkmcnt(0)" ::: "memory"); \
                    __builtin_amdgcn_s_barrier();                      \
                    asm volatile("" ::: "memory"); } while (0)

// async global->LDS, 16B per lane. LDS dest is wave-uniform base + lane*16;
// global src is per-lane (guide §5 / m97).
__device__ __forceinline__ void gl_lds16(const void* g, void* l) {
    __builtin_amdgcn_global_load_lds(
        (const __attribute__((address_space(1))) unsigned int*)g,
        (__attribute__((address_space(3))) unsigned int*)l, 16, 0, 0);
}

// ---------------------------------------------------------------------------
// pack w_ih1 (700x128, zero-pad K to 704) into MFMA B-frag order, hi/lo bf16.
// frag element (k,c): dst_frag = (kt*8+nt)*64 + qq*16+li, elem j   (unchanged)
// ---------------------------------------------------------------------------
__global__ __launch_bounds__(256) void packw(const float* __restrict__ w,
                                             unsigned short* __restrict__ ph,
                                             unsigned short* __restrict__ pl) {
    int i = blockIdx.x * 256 + threadIdx.x;   // 352*256 = 90112 = 704*128
    int k = i >> 7, c = i & 127;
    float v = (k < KIN) ? w[k * HN + c] : 0.f;
    short h, l;
    hilo(v, h, l);
    int dst = (((k >> 5) * 8 + (c >> 4)) * 64 + (((k >> 3) & 3) * 16 + (c & 15))) * 8 + (k & 7);
    ph[dst] = (unsigned short)h;
    pl[dst] = (unsigned short)l;
}

// ---------------------------------------------------------------------------
// input projection v2: m97-style. Weights staged to LDS per-kt via
// global_load_lds (double buffered, 2x16KB); x chunk prefetched one kt ahead
// in registers. Numerics (hilo split + MFMA order) bit-identical to v1.
// ---------------------------------------------------------------------------
__device__ __forceinline__ void stage_kt(const unsigned short* __restrict__ wph,
                                         const unsigned short* __restrict__ wpl,
                                         void* buf, int kt, int tid) {
    const char* sh = (const char*)wph + kt * 8192 + tid * 16;
    const char* sl = (const char*)wpl + kt * 8192 + tid * 16;
    char* b = (char*)buf;
    const int wb = (tid >> 6) * 1024;   // wave-uniform LDS base
    gl_lds16(sh,        b + wb);
    gl_lds16(sh + 4096, b + wb + 4096);
    gl_lds16(sl,        b + wb + 8192);
    gl_lds16(sl + 4096, b + wb + 12288);
}

__device__ __forceinline__ void loadx8(float* av, const float* p, bool tailq3) {
    *(float4*)&av[0] = *(const float4*)p;
    if (tailq3) {
        av[4] = 0.f; av[5] = 0.f; av[6] = 0.f; av[7] = 0.f;
    } else {
        *(float4*)&av[4] = *(const float4*)(p + 4);
    }
}

__global__ __launch_bounds__(256, 4) void gemm_in(const float* __restrict__ x,
        const unsigned short* __restrict__ wph, const unsigned short* __restrict__ wpl,
        const float* __restrict__ bias1, const float* __restrict__ bias2,
        float* __restrict__ xin) {
    __shared__ __align__(16) unsigned char wbuf[2][16384];   // 32 KB
    const int tid = threadIdx.x;
    const int w = tid >> 6, lane = tid & 63;
    const int q = lane >> 4, li = lane & 15;
    const long mrow = (long)blockIdx.x * 64 + w * 16 + li;
    const float* xr = x + mrow * KIN + q * 8;

    f32x4 acc[8];
#pragma unroll
    for (int nt = 0; nt < 8; nt++) acc[nt] = (f32x4){0.f, 0.f, 0.f, 0.f};

    // prologue: stage kt=0, load x chunk 0
    stage_kt(wph, wpl, wbuf[0], 0, tid);
    float av[8];
    loadx8(av, xr, false);
    __syncthreads();   // drains stage(0) (vmcnt0) + barrier

#pragma unroll 2
    for (int kt = 0; kt < NKT; kt++) {
        // issue next-tile staging + next x chunk first (in flight over compute)
        if (kt + 1 < NKT)
            stage_kt(wph, wpl, wbuf[(kt + 1) & 1], kt + 1, tid);
        float avn[8];
        if (kt + 1 < NKT)
            loadx8(avn, xr + (kt + 1) * 32, (kt + 1 == NKT - 1) && (q == 3));

        // convert current x chunk to hi/lo bf16 (same rounding as v1)
        bf16x8 ah, al;
#pragma unroll
        for (int j = 0; j < 8; j++) {
            short h, l;
            hilo(av[j], h, l);
            ah[j] = h; al[j] = l;
        }

        // MFMA over the 8 col-tiles, B frags from LDS
        const bf16x8* cv = (const bf16x8*)&wbuf[kt & 1][0];
#pragma unroll 2
        for (int nt = 0; nt < 8; nt++) {
            bf16x8 bh = cv[nt * 64 + lane];
            bf16x8 bl = cv[512 + nt * 64 + lane];
            acc[nt] = __builtin_amdgcn_mfma_f32_16x16x32_bf16(ah, bh, acc[nt], 0, 0, 0);
            acc[nt] = __builtin_amdgcn_mfma_f32_16x16x32_bf16(al, bh, acc[nt], 0, 0, 0);
            acc[nt] = __builtin_amdgcn_mfma_f32_16x16x32_bf16(ah, bl, acc[nt], 0, 0, 0);
        }

        if (kt + 1 < NKT) {
#pragma unroll
            for (int j = 0; j < 8; j++) av[j] = avn[j];
        }
        __syncthreads();   // stage(kt+1) complete + all reads of cur done
    }

    // epilogue: biases folded in here (b_ih1 + b_h1h1)
    float b12[8];
#pragma unroll
    for (int nt = 0; nt < 8; nt++) {
        int c = nt * 16 + li;
        b12[nt] = bias1[c] + bias2[c];
    }
#pragma unroll
    for (int r = 0; r < 4; r++) {
        int m = blockIdx.x * 64 + w * 16 + q * 4 + r;
        int bq = (int)(((unsigned long long)m * 67109ull) >> 24);  // m/250, exact for m<3.2M
        int tt = m - bq * 250;
        float* dst = xin + ((size_t)tt * BT + bq) * HN;
#pragma unroll
        for (int nt = 0; nt < 8; nt++) dst[nt * 16 + li] = acc[nt][r] + b12[nt];
    }
}

// ---------------------------------------------------------------------------
// scan v6: 16 blocks x 512 thr. Changes vs v5:
//  - __launch_bounds__(512,1): 256-VGPR budget (weight frags ~128 regs no
//    longer force AGPR shuffling), 1 block/CU -> 16 CUs.
//  - xt prefetched one full step ahead; in-loop barriers are lgkm-only raw
//    s_barrier so the HBM prefetch stays in flight across them.
//  - phase-1 f1 frags == previous step's g1 frags -> carried in registers
//    (removes 4 ds_read_b128 + LDS latency from phase-1 critical path).
// All arithmetic unchanged.
// ---------------------------------------------------------------------------
__global__ __launch_bounds__(512, 1) void snn_scan(
    const float* __restrict__ xin, const float* __restrict__ mask,
    const float* __restrict__ w_h1h1, const float* __restrict__ w_h1h2,
    const float* __restrict__ b_h1h2, const float* __restrict__ w_h2h2,
    const float* __restrict__ b_h2h2, const float* __restrict__ w_h2o,
    const float* __restrict__ b_h2o, const float* __restrict__ tau_adp1,
    const float* __restrict__ tau_adp2, const float* __restrict__ taum1,
    const float* __restrict__ taum2, const float* __restrict__ taumo,
    const float* __restrict__ h1m0, const float* __restrict__ h2m0,
    const float* __restrict__ om0, float* __restrict__ out) {

    __shared__ __align__(16) unsigned short sA1[2 * 2048];  // S1 frags, dbuf
    __shared__ __align__(16) unsigned short sA2[2048];      // S2 frags
    __shared__ float omb[16 * ON];
    __shared__ float red[8];

    const int tid = threadIdx.x;
    const int w = tid >> 6, lane = tid & 63;
    const int q = lane >> 4, li = lane & 15;
    const int col = w * 16 + li;          // this lane's neuron column
    const int r0 = blockIdx.x * 16;       // batch-row base

    // ---- weight fragments (register-resident, hi/lo bf16) ----
    bf16x8 h11[4], l11[4], h22[4], l22[4], h12[4], l12[4], hO[4], lO[4];
    const int ocol = (w == 6) ? li : 16 + li;         // WHO col (w6: 0-15, w7: 16-19)
    const bool oval = (w >= 6) && (ocol < ON);
    float pn = 0.f;
#pragma unroll
    for (int kt = 0; kt < 4; kt++) {
#pragma unroll
        for (int j = 0; j < 8; j++) {
            const int k = kt * 32 + q * 8 + j;
            const int idx = k * HN + col;
            float v11 = w_h1h1[idx] * mask[idx];
            float v22 = w_h2h2[idx] * mask[HN * HN + idx];
            float v12 = w_h1h2[idx];
            pn += fabsf(v11) + fabsf(v22);
            short hh, ll;
            hilo(v11, hh, ll); h11[kt][j] = hh; l11[kt][j] = ll;
            hilo(v22, hh, ll); h22[kt][j] = hh; l22[kt][j] = ll;
            hilo(v12, hh, ll); h12[kt][j] = hh; l12[kt][j] = ll;
            float vO = oval ? w_h2o[k * ON + ocol] : 0.f;
            hilo(vO, hh, ll); hO[kt][j] = hh; lO[kt][j] = ll;
        }
    }

    // ---- per-lane constants & state (4 rows x 1 col each) ----
    const float a1 = expf(-1.f / taum1[col]);
    const float r1 = expf(-1.f / tau_adp1[col]);
    const float a2 = expf(-1.f / taum2[col]);
    const float r2 = expf(-1.f / tau_adp2[col]);
    const float cc2 = b_h1h2[col] + b_h2h2[col];
    float h1m[4], h2m[4], b1[4], b2[4], c1[4], c2n[4];
    unsigned s1bits = 0, s2bits = 0;
#pragma unroll
    for (int r = 0; r < 4; r++) {
        h1m[r] = h1m0[(r0 + q * 4 + r) * HN + col];
        h2m[r] = h2m0[(r0 + q * 4 + r) * HN + col];
        b1[r] = 0.01f; b2[r] = 0.01f; c1[r] = 0.f; c2n[r] = 0.f;
    }
    const float ao = oval ? expf(-1.f / taumo[ocol]) : 0.f;
    const float bo = oval ? b_h2o[ocol] : 0.f;
    float om[4];
#pragma unroll
    for (int r = 0; r < 4; r++)
        om[r] = oval ? om0[(r0 + q * 4 + r) * ON + ocol] : 0.f;
    const int sm = lane >> 2, ob = (lane & 3) * 5;    // w7 softmax roles
    float accs[5] = {0.f, 0.f, 0.f, 0.f, 0.f};

    // zero spike frags (both buffers of sA1, sA2)
    {
        unsigned* z1 = (unsigned*)sA1;
        unsigned* z2 = (unsigned*)sA2;
        z1[tid] = 0u; z1[tid + 512] = 0u;
        z2[tid] = 0u; z2[tid + 512] = 0u;
    }

    // A_norm: exact f32 sum of |masked| weights, each element once
#pragma unroll
    for (int off = 32; off > 0; off >>= 1) pn += __shfl_down(pn, off);
    if (lane == 0) red[w] = pn;
    __syncthreads();
    if (tid == 0 && blockIdx.x == 0) {
        float s = 0.f;
#pragma unroll
        for (int i = 0; i < 8; i++) s += red[i];
        out[70656] = s;
    }

    // spike frag write index (this lane's 4 elements: +r*8)
    const int wbase = (w >> 1) * 512 + (((2 * w + (li >> 3)) & 3) * 16 + q * 4) * 8 + (li & 7);

    const bf16x8* sa1v = (const bf16x8*)sA1;
    const bf16x8* sa2v = (const bf16x8*)sA2;
    const unsigned short ONE = 0x3F80u;

    // f1 carry (S1 frags of previous step); buffer 0 is zeroed -> zero frags
    bf16x8 f1c[4];
    const bf16x8 zf = {0, 0, 0, 0, 0, 0, 0, 0};
#pragma unroll
    for (int kt = 0; kt < 4; kt++) f1c[kt] = zf;

    // xt prefetch: preload t=0
    float xt[4], xtn[4];
#pragma unroll
    for (int r = 0; r < 4; r++)
        xt[r] = xin[((size_t)0 * BT + r0 + q * 4 + r) * HN + col];

    for (int t = 0; t < TT; t++) {
        const int wb = ((t + 1) & 1) * 2048;   // sA1 write base (shorts)

        // issue next-step xin prefetch (stays in flight across lgkm barriers)
        const int tn = (t + 1 < TT) ? t + 1 : t;
#pragma unroll
        for (int r = 0; r < 4; r++)
            xtn[r] = xin[((size_t)tn * BT + r0 + q * 4 + r) * HN + col];

        // ================= phase 1 =================
        bf16x8 f2[4];
#pragma unroll
        for (int kt = 0; kt < 4; kt++) f2[kt] = sa2v[kt * 64 + lane];
        f32x4 aI = {0.f, 0.f, 0.f, 0.f}, aG = {0.f, 0.f, 0.f, 0.f};
#pragma unroll
        for (int kt = 0; kt < 4; kt++) {
            aI = __builtin_amdgcn_mfma_f32_16x16x32_bf16(f1c[kt], h11[kt], aI, 0, 0, 0);
            aI = __builtin_amdgcn_mfma_f32_16x16x32_bf16(f1c[kt], l11[kt], aI, 0, 0, 0);
            aG = __builtin_amdgcn_mfma_f32_16x16x32_bf16(f2[kt], h22[kt], aG, 0, 0, 0);
            aG = __builtin_amdgcn_mfma_f32_16x16x32_bf16(f2[kt], l22[kt], aG, 0, 0, 0);
        }
        if (w >= 6) {
            f32x4 aO = {0.f, 0.f, 0.f, 0.f};
#pragma unroll
            for (int kt = 0; kt < 4; kt++) {
                aO = __builtin_amdgcn_mfma_f32_16x16x32_bf16(f2[kt], hO[kt], aO, 0, 0, 0);
                aO = __builtin_amdgcn_mfma_f32_16x16x32_bf16(f2[kt], lO[kt], aO, 0, 0, 0);
            }
            if (t >= 1) {   // om update for step t-1 (io = S2(t-1)@WHO)
#pragma unroll
                for (int r = 0; r < 4; r++) {
                    om[r] = ao * om[r] + (1.f - ao) * (bo + aO[r]);
                    if (oval) omb[(q * 4 + r) * ON + ocol] = om[r];
                }
            }
        }
        // layer-1 LIF update (in C-layout: rows q*4+r, col)
#pragma unroll
        for (int r = 0; r < 4; r++) {
            const float sv = (float)((s1bits >> r) & 1u);
            const float i1 = xt[r] + aI[r];       // biases folded into xin
            b1[r] = r1 * b1[r] + (1.f - r1) * sv;
            const float B = 0.01f + 1.8f * b1[r];
            h1m[r] = a1 * h1m[r] + (1.f - a1) * i1 - B * sv;
            const bool sp = (h1m[r] - B) > 0.f;
            s1bits = sp ? (s1bits | (1u << r)) : (s1bits & ~(1u << r));
            c1[r] += sp ? 1.f : 0.f;
            sA1[wb + wbase + r * 8] = sp ? ONE : (unsigned short)0;
        }
        LBAR();  // B1: S1 frags + omb ready (lgkm-only; xin prefetch rides over)

        // ================= phase 2 =================
        bf16x8 g1[4];
#pragma unroll
        for (int kt = 0; kt < 4; kt++) g1[kt] = sa1v[(wb >> 3) + kt * 64 + lane];
        f32x4 aJ = {0.f, 0.f, 0.f, 0.f};
#pragma unroll
        for (int kt = 0; kt < 4; kt++) {
            aJ = __builtin_amdgcn_mfma_f32_16x16x32_bf16(g1[kt], h12[kt], aJ, 0, 0, 0);
            aJ = __builtin_amdgcn_mfma_f32_16x16x32_bf16(g1[kt], l12[kt], aJ, 0, 0, 0);
        }
        if (w == 7 && t >= 12) {   // softmax accumulate for step t-1
            float v[5], e[5];
            float mx = -1e30f;
#pragma unroll
            for (int i = 0; i < 5; i++) { v[i] = omb[sm * ON + ob + i]; mx = fmaxf(mx, v[i]); }
            mx = fmaxf(mx, __shfl_xor(mx, 1));
            mx = fmaxf(mx, __shfl_xor(mx, 2));
            float se = 0.f;
#pragma unroll
            for (int i = 0; i < 5; i++) { e[i] = __expf(v[i] - mx); se += e[i]; }
            se += __shfl_xor(se, 1);
            se += __shfl_xor(se, 2);
            const float inv = 1.f / se;
#pragma unroll
            for (int i = 0; i < 5; i++) accs[i] += e[i] * inv;
        }
        // layer-2 LIF update
#pragma unroll
        for (int r = 0; r < 4; r++) {
            const float sv = (float)((s2bits >> r) & 1u);
            const float i2 = aJ[r] + aG[r] + cc2;
            b2[r] = r2 * b2[r] + (1.f - r2) * sv;
            const float B = 0.01f + 1.8f * b2[r];
            h2m[r] = a2 * h2m[r] + (1.f - a2) * i2 - B * sv;
            const bool sp = (h2m[r] - B) > 0.f;
            s2bits = sp ? (s2bits | (1u << r)) : (s2bits & ~(1u << r));
            c2n[r] += sp ? 1.f : 0.f;
            sA2[wbase + r * 8] = sp ? ONE : (unsigned short)0;
        }
        // carry: f1(t+1) == g1(t)  (same buffer, same data)
#pragma unroll
        for (int kt = 0; kt < 4; kt++) f1c[kt] = g1[kt];
#pragma unroll
        for (int r = 0; r < 4; r++) xt[r] = xtn[r];
        LBAR();  // B2: S2 frags ready
    }

    // ---- tail: om + softmax for step 249 ----
    if (w >= 6) {
        bf16x8 f2[4];
#pragma unroll
        for (int kt = 0; kt < 4; kt++) f2[kt] = sa2v[kt * 64 + lane];
        f32x4 aO = {0.f, 0.f, 0.f, 0.f};
#pragma unroll
        for (int kt = 0; kt < 4; kt++) {
            aO = __builtin_amdgcn_mfma_f32_16x16x32_bf16(f2[kt], hO[kt], aO, 0, 0, 0);
            aO = __builtin_amdgcn_mfma_f32_16x16x32_bf16(f2[kt], lO[kt], aO, 0, 0, 0);
        }
#pragma unroll
        for (int r = 0; r < 4; r++) {
            om[r] = ao * om[r] + (1.f - ao) * (bo + aO[r]);
            if (oval) omb[(q * 4 + r) * ON + ocol] = om[r];
        }
    }
    __syncthreads();
    if (w == 7) {
        float v[5], e[5];
        float mx = -1e30f;
#pragma unroll
        for (int i = 0; i < 5; i++) { v[i] = omb[sm * ON + ob + i]; mx = fmaxf(mx, v[i]); }
        mx = fmaxf(mx, __shfl_xor(mx, 1));
        mx = fmaxf(mx, __shfl_xor(mx, 2));
        float se = 0.f;
#pragma unroll
        for (int i = 0; i < 5; i++) { e[i] = __expf(v[i] - mx); se += e[i]; }
        se += __shfl_xor(se, 1);
        se += __shfl_xor(se, 2);
        const float inv = 1.f / se;
#pragma unroll
        for (int i = 0; i < 5; i++) out[(r0 + sm) * ON + ob + i] = accs[i] + e[i] * inv;
    }
    // spike rates
#pragma unroll
    for (int r = 0; r < 4; r++) {
        out[5120 + (r0 + q * 4 + r) * HN + col] = c1[r] * (1.f / 250.f);
        out[37888 + (r0 + q * 4 + r) * HN + col] = c2n[r] * (1.f / 250.f);
    }
}

// ---------------------------------------------------------------------------
extern "C" void kernel_launch(void* const* d_in, const int* in_sizes, int n_in,
                              void* d_out, int out_size, void* d_ws, size_t ws_size,
                              hipStream_t stream) {
    const float* x        = (const float*)d_in[0];
    const float* mask     = (const float*)d_in[1];
    const float* w_ih1    = (const float*)d_in[2];
    const float* b_ih1    = (const float*)d_in[3];
    const float* w_h1h1   = (const float*)d_in[4];
    const float* b_h1h1   = (const float*)d_in[5];
    const float* w_h1h2   = (const float*)d_in[6];
    const float* b_h1h2   = (const float*)d_in[7];
    const float* w_h2h2   = (const float*)d_in[8];
    const float* b_h2h2   = (const float*)d_in[9];
    const float* w_h2o    = (const float*)d_in[10];
    const float* b_h2o    = (const float*)d_in[11];
    const float* tau_adp1 = (const float*)d_in[12];
    const float* tau_adp2 = (const float*)d_in[13];
    const float* taum1    = (const float*)d_in[14];
    const float* taum2    = (const float*)d_in[15];
    const float* taumo    = (const float*)d_in[16];
    const float* h1m0     = (const float*)d_in[17];
    const float* h2m0     = (const float*)d_in[18];
    const float* om0      = (const float*)d_in[19];
    float* out = (float*)d_out;
    float* ws  = (float*)d_ws;

    float* xin = ws + XIN_OFF;
    unsigned short* wph = (unsigned short*)(ws + WPKH_OFF);
    unsigned short* wpl = (unsigned short*)(ws + WPKL_OFF);

    packw<<<352, 256, 0, stream>>>(w_ih1, wph, wpl);
    gemm_in<<<1000, 256, 0, stream>>>(x, wph, wpl, b_ih1, b_h1h1, xin);
    snn_scan<<<16, 512, 0, stream>>>(xin, mask, w_h1h1, w_h1h2, b_h1h2, w_h2h2,
                                     b_h2h2, w_h2o, b_h2o, tau_adp1, tau_adp2,
                                     taum1, taum2, taumo, h1m0, h2m0, om0, out);
}

// Round 2
// 609.727 us; speedup vs baseline: 1.0754x; 1.0438x over previous
//
#include <hip/hip_runtime.h>
#include <math.h>

#define TT 250
#define BT 256
#define HN 128
#define ON 20
#define KIN 700
#define NKT 22

// ws layout (float offsets): xin[250*256*128] | packed W hi | packed W lo
#define XIN_OFF 0
#define WPKH_OFF 8192000   // 45056 floats (90112 bf16)
#define WPKL_OFF 8237056   // 45056 floats

typedef __attribute__((ext_vector_type(8))) short bf16x8;
typedef __attribute__((ext_vector_type(4))) float f32x4;

__device__ __forceinline__ unsigned short bf16rne(float f) {
    unsigned u = __float_as_uint(f);
    unsigned r = u + 0x7fffu + ((u >> 16) & 1u);
    return (unsigned short)(r >> 16);
}
__device__ __forceinline__ void hilo(float v, short& h, short& l) {
    unsigned short hh = bf16rne(v);
    float vh = __uint_as_float((unsigned)hh << 16);
    h = (short)hh;
    l = (short)bf16rne(v - vh);
}

// async global->LDS, 16B per lane. LDS dest is wave-uniform base + lane*16;
// global src is per-lane (guide §5 / m97).
__device__ __forceinline__ void gl_lds16(const void* g, void* l) {
    __builtin_amdgcn_global_load_lds(
        (const __attribute__((address_space(1))) unsigned int*)g,
        (__attribute__((address_space(3))) unsigned int*)l, 16, 0, 0);
}

// ---------------------------------------------------------------------------
// pack w_ih1 (700x128, zero-pad K to 704) into MFMA B-frag order, hi/lo bf16.
// frag element (k,c): dst_frag = (kt*8+nt)*64 + qq*16+li, elem j   (unchanged)
// ---------------------------------------------------------------------------
__global__ __launch_bounds__(256) void packw(const float* __restrict__ w,
                                             unsigned short* __restrict__ ph,
                                             unsigned short* __restrict__ pl) {
    int i = blockIdx.x * 256 + threadIdx.x;   // 352*256 = 90112 = 704*128
    int k = i >> 7, c = i & 127;
    float v = (k < KIN) ? w[k * HN + c] : 0.f;
    short h, l;
    hilo(v, h, l);
    int dst = (((k >> 5) * 8 + (c >> 4)) * 64 + (((k >> 3) & 3) * 16 + (c & 15))) * 8 + (k & 7);
    ph[dst] = (unsigned short)h;
    pl[dst] = (unsigned short)l;
}

// ---------------------------------------------------------------------------
// input projection v3: 500 blocks x 128 rows. Each staged 16KB weight tile is
// reused by 2 row-chunks (halves redundant weight traffic vs v2 and doubles
// compute per barrier). x prefetched TWO chunk-phases ahead (~HBM latency)
// into a static av[2][8] ring, no copies. Numerics identical to v1/v2.
// ---------------------------------------------------------------------------
__device__ __forceinline__ void stage_kt(const unsigned short* __restrict__ wph,
                                         const unsigned short* __restrict__ wpl,
                                         void* buf, int kt, int tid) {
    const char* sh = (const char*)wph + kt * 8192 + tid * 16;
    const char* sl = (const char*)wpl + kt * 8192 + tid * 16;
    char* b = (char*)buf;
    const int wb = (tid >> 6) * 1024;   // wave-uniform LDS base
    gl_lds16(sh,        b + wb);
    gl_lds16(sh + 4096, b + wb + 4096);
    gl_lds16(sl,        b + wb + 8192);
    gl_lds16(sl + 4096, b + wb + 12288);
}

__device__ __forceinline__ void loadx8(float* av, const float* p, bool tailq3) {
    *(float4*)&av[0] = *(const float4*)p;
    if (tailq3) {
        av[4] = 0.f; av[5] = 0.f; av[6] = 0.f; av[7] = 0.f;
    } else {
        *(float4*)&av[4] = *(const float4*)(p + 4);
    }
}

__global__ __launch_bounds__(256, 2) void gemm_in(const float* __restrict__ x,
        const unsigned short* __restrict__ wph, const unsigned short* __restrict__ wpl,
        const float* __restrict__ bias1, const float* __restrict__ bias2,
        float* __restrict__ xin) {
    __shared__ __align__(16) unsigned char wbuf[2][16384];   // 32 KB
    const int tid = threadIdx.x;
    const int w = tid >> 6, lane = tid & 63;
    const int q = lane >> 4, li = lane & 15;
    const long mbase = (long)blockIdx.x * 128;
    const float* xr0 = x + (mbase + w * 16 + li) * KIN + q * 8;

    f32x4 acc[2][8];
#pragma unroll
    for (int c = 0; c < 2; c++)
#pragma unroll
        for (int nt = 0; nt < 8; nt++) acc[c][nt] = (f32x4){0.f, 0.f, 0.f, 0.f};

    // prologue: stage kt=0; preload x for phases (0,0) and (0,1)
    stage_kt(wph, wpl, wbuf[0], 0, tid);
    float av[2][8];
    loadx8(av[0], xr0, false);
    loadx8(av[1], xr0 + 64 * KIN, false);
    __syncthreads();   // drains stage(0)

    for (int kt = 0; kt < NKT; kt++) {
        if (kt + 1 < NKT)
            stage_kt(wph, wpl, wbuf[(kt + 1) & 1], kt + 1, tid);
        const bf16x8* cv = (const bf16x8*)&wbuf[kt & 1][0];
#pragma unroll
        for (int c = 0; c < 2; c++) {
            // convert current x chunk (same rounding as v1)
            bf16x8 ah, al;
#pragma unroll
            for (int j = 0; j < 8; j++) {
                short h, l;
                hilo(av[c][j], h, l);
                ah[j] = h; al[j] = l;
            }
            // issue this slot's next load (phase +2 => ~full HBM latency cover)
            if (kt + 1 < NKT)
                loadx8(av[c], xr0 + c * (64 * KIN) + (kt + 1) * 32,
                       (kt + 1 == NKT - 1) && (q == 3));
#pragma unroll
            for (int nt = 0; nt < 8; nt++) {
                bf16x8 bh = cv[nt * 64 + lane];
                bf16x8 bl = cv[512 + nt * 64 + lane];
                acc[c][nt] = __builtin_amdgcn_mfma_f32_16x16x32_bf16(ah, bh, acc[c][nt], 0, 0, 0);
                acc[c][nt] = __builtin_amdgcn_mfma_f32_16x16x32_bf16(al, bh, acc[c][nt], 0, 0, 0);
                acc[c][nt] = __builtin_amdgcn_mfma_f32_16x16x32_bf16(ah, bl, acc[c][nt], 0, 0, 0);
            }
        }
        __syncthreads();   // stage(kt+1) complete + all reads of cur done
    }

    // epilogue: biases folded in here (b_ih1 + b_h1h1)
    float b12[8];
#pragma unroll
    for (int nt = 0; nt < 8; nt++) {
        int c = nt * 16 + li;
        b12[nt] = bias1[c] + bias2[c];
    }
#pragma unroll
    for (int c = 0; c < 2; c++) {
#pragma unroll
        for (int r = 0; r < 4; r++) {
            long m = mbase + c * 64 + w * 16 + q * 4 + r;
            int bq = (int)(((unsigned long long)m * 67109ull) >> 24);  // m/250, exact for m<3.2M
            int tt = (int)m - bq * 250;
            float* dst = xin + ((size_t)tt * BT + bq) * HN;
#pragma unroll
            for (int nt = 0; nt < 8; nt++) dst[nt * 16 + li] = acc[c][nt][r] + b12[nt];
        }
    }
}

// ---------------------------------------------------------------------------
// scan v7: 16 blocks x 512 thr, __syncthreads barriers (v5 scheduling), plus:
//  - g1 (S1 frags read in phase 2) PERSISTS in registers and serves as
//    phase-1's f1 next step: no f1 LDS read, no copies.
//  - single sA1 buffer (double-buffer was vestigial once f1 is reg-carried).
//  - xin addressed via one incremented base pointer (no per-step 64b muls).
//  - softmax moved w7 -> w0 (w6/w7 already carry aO+om in phase 1).
// Arithmetic order identical to v5 => absmax unchanged.
// ---------------------------------------------------------------------------
__global__ __launch_bounds__(512, 2) void snn_scan(
    const float* __restrict__ xin, const float* __restrict__ mask,
    const float* __restrict__ w_h1h1, const float* __restrict__ w_h1h2,
    const float* __restrict__ b_h1h2, const float* __restrict__ w_h2h2,
    const float* __restrict__ b_h2h2, const float* __restrict__ w_h2o,
    const float* __restrict__ b_h2o, const float* __restrict__ tau_adp1,
    const float* __restrict__ tau_adp2, const float* __restrict__ taum1,
    const float* __restrict__ taum2, const float* __restrict__ taumo,
    const float* __restrict__ h1m0, const float* __restrict__ h2m0,
    const float* __restrict__ om0, float* __restrict__ out) {

    __shared__ __align__(16) unsigned short sA1[2048];      // S1 frags
    __shared__ __align__(16) unsigned short sA2[2048];      // S2 frags
    __shared__ float omb[16 * ON];
    __shared__ float red[8];

    const int tid = threadIdx.x;
    const int w = tid >> 6, lane = tid & 63;
    const int q = lane >> 4, li = lane & 15;
    const int col = w * 16 + li;          // this lane's neuron column
    const int r0 = blockIdx.x * 16;       // batch-row base

    // ---- weight fragments (register-resident, hi/lo bf16) ----
    bf16x8 h11[4], l11[4], h22[4], l22[4], h12[4], l12[4], hO[4], lO[4];
    const int ocol = (w == 6) ? li : 16 + li;         // WHO col (w6: 0-15, w7: 16-19)
    const bool oval = (w >= 6) && (ocol < ON);
    float pn = 0.f;
#pragma unroll
    for (int kt = 0; kt < 4; kt++) {
#pragma unroll
        for (int j = 0; j < 8; j++) {
            const int k = kt * 32 + q * 8 + j;
            const int idx = k * HN + col;
            float v11 = w_h1h1[idx] * mask[idx];
            float v22 = w_h2h2[idx] * mask[HN * HN + idx];
            float v12 = w_h1h2[idx];
            pn += fabsf(v11) + fabsf(v22);
            short hh, ll;
            hilo(v11, hh, ll); h11[kt][j] = hh; l11[kt][j] = ll;
            hilo(v22, hh, ll); h22[kt][j] = hh; l22[kt][j] = ll;
            hilo(v12, hh, ll); h12[kt][j] = hh; l12[kt][j] = ll;
            float vO = oval ? w_h2o[k * ON + ocol] : 0.f;
            hilo(vO, hh, ll); hO[kt][j] = hh; lO[kt][j] = ll;
        }
    }

    // ---- per-lane constants & state (4 rows x 1 col each) ----
    const float a1 = expf(-1.f / taum1[col]);
    const float r1 = expf(-1.f / tau_adp1[col]);
    const float a2 = expf(-1.f / taum2[col]);
    const float r2 = expf(-1.f / tau_adp2[col]);
    const float cc2 = b_h1h2[col] + b_h2h2[col];
    float h1m[4], h2m[4], b1[4], b2[4], c1[4], c2n[4];
    unsigned s1bits = 0, s2bits = 0;
#pragma unroll
    for (int r = 0; r < 4; r++) {
        h1m[r] = h1m0[(r0 + q * 4 + r) * HN + col];
        h2m[r] = h2m0[(r0 + q * 4 + r) * HN + col];
        b1[r] = 0.01f; b2[r] = 0.01f; c1[r] = 0.f; c2n[r] = 0.f;
    }
    const float ao = oval ? expf(-1.f / taumo[ocol]) : 0.f;
    const float bo = oval ? b_h2o[ocol] : 0.f;
    float om[4];
#pragma unroll
    for (int r = 0; r < 4; r++)
        om[r] = oval ? om0[(r0 + q * 4 + r) * ON + ocol] : 0.f;
    const int sm = lane >> 2, ob = (lane & 3) * 5;    // w0 softmax roles
    float accs[5] = {0.f, 0.f, 0.f, 0.f, 0.f};

    // zero spike frags
    {
        unsigned* z1 = (unsigned*)sA1;
        unsigned* z2 = (unsigned*)sA2;
        z1[tid & 511] = 0u; z1[(tid & 511) + 512] = 0u;
        z2[tid & 511] = 0u; z2[(tid & 511) + 512] = 0u;
    }

    // A_norm: exact f32 sum of |masked| weights, each element once
#pragma unroll
    for (int off = 32; off > 0; off >>= 1) pn += __shfl_down(pn, off);
    if (lane == 0) red[w] = pn;
    __syncthreads();
    if (tid == 0 && blockIdx.x == 0) {
        float s = 0.f;
#pragma unroll
        for (int i = 0; i < 8; i++) s += red[i];
        out[70656] = s;
    }

    // spike frag write index (this lane's 4 elements: +r*8)
    const int wbase = (w >> 1) * 512 + (((2 * w + (li >> 3)) & 3) * 16 + q * 4) * 8 + (li & 7);

    const bf16x8* sa1v = (const bf16x8*)sA1;
    const bf16x8* sa2v = (const bf16x8*)sA2;
    const unsigned short ONE = 0x3F80u;

    // g1 = S1 frags of previous step (register-carried); S1(-1) = 0
    bf16x8 g1[4];
    const bf16x8 zf = {0, 0, 0, 0, 0, 0, 0, 0};
#pragma unroll
    for (int kt = 0; kt < 4; kt++) g1[kt] = zf;

    // xin running pointer: rows r0+q*4+r, col; +BT*HN per step
    const float* xp = xin + (size_t)(r0 + q * 4) * HN + col;

    for (int t = 0; t < TT; t++) {
        // xt loads for this step (consumed after the MFMA chains, no barrier between)
        float xt[4];
#pragma unroll
        for (int r = 0; r < 4; r++) xt[r] = xp[r * HN];
        xp += BT * HN;

        // ================= phase 1 =================
        bf16x8 f2[4];
#pragma unroll
        for (int kt = 0; kt < 4; kt++) f2[kt] = sa2v[kt * 64 + lane];
        f32x4 aI = {0.f, 0.f, 0.f, 0.f}, aG = {0.f, 0.f, 0.f, 0.f};
#pragma unroll
        for (int kt = 0; kt < 4; kt++) {
            aI = __builtin_amdgcn_mfma_f32_16x16x32_bf16(g1[kt], h11[kt], aI, 0, 0, 0);
            aI = __builtin_amdgcn_mfma_f32_16x16x32_bf16(g1[kt], l11[kt], aI, 0, 0, 0);
            aG = __builtin_amdgcn_mfma_f32_16x16x32_bf16(f2[kt], h22[kt], aG, 0, 0, 0);
            aG = __builtin_amdgcn_mfma_f32_16x16x32_bf16(f2[kt], l22[kt], aG, 0, 0, 0);
        }
        if (w >= 6) {
            f32x4 aO = {0.f, 0.f, 0.f, 0.f};
#pragma unroll
            for (int kt = 0; kt < 4; kt++) {
                aO = __builtin_amdgcn_mfma_f32_16x16x32_bf16(f2[kt], hO[kt], aO, 0, 0, 0);
                aO = __builtin_amdgcn_mfma_f32_16x16x32_bf16(f2[kt], lO[kt], aO, 0, 0, 0);
            }
            if (t >= 1) {   // om update for step t-1 (io = S2(t-1)@WHO)
#pragma unroll
                for (int r = 0; r < 4; r++) {
                    om[r] = ao * om[r] + (1.f - ao) * (bo + aO[r]);
                    if (oval) omb[(q * 4 + r) * ON + ocol] = om[r];
                }
            }
        }
        // layer-1 LIF update (in C-layout: rows q*4+r, col)
#pragma unroll
        for (int r = 0; r < 4; r++) {
            const float sv = (float)((s1bits >> r) & 1u);
            const float i1 = xt[r] + aI[r];       // biases folded into xin
            b1[r] = r1 * b1[r] + (1.f - r1) * sv;
            const float B = 0.01f + 1.8f * b1[r];
            h1m[r] = a1 * h1m[r] + (1.f - a1) * i1 - B * sv;
            const bool sp = (h1m[r] - B) > 0.f;
            s1bits = sp ? (s1bits | (1u << r)) : (s1bits & ~(1u << r));
            c1[r] += sp ? 1.f : 0.f;
            sA1[wbase + r * 8] = sp ? ONE : (unsigned short)0;
        }
        __syncthreads();  // B1: S1 frags + omb ready

        // ================= phase 2 =================
#pragma unroll
        for (int kt = 0; kt < 4; kt++) g1[kt] = sa1v[kt * 64 + lane];
        f32x4 aJ = {0.f, 0.f, 0.f, 0.f};
#pragma unroll
        for (int kt = 0; kt < 4; kt++) {
            aJ = __builtin_amdgcn_mfma_f32_16x16x32_bf16(g1[kt], h12[kt], aJ, 0, 0, 0);
            aJ = __builtin_amdgcn_mfma_f32_16x16x32_bf16(g1[kt], l12[kt], aJ, 0, 0, 0);
        }
        if (w == 0 && t >= 12) {   // softmax accumulate for step t-1
            float v[5], e[5];
            float mx = -1e30f;
#pragma unroll
            for (int i = 0; i < 5; i++) { v[i] = omb[sm * ON + ob + i]; mx = fmaxf(mx, v[i]); }
            mx = fmaxf(mx, __shfl_xor(mx, 1));
            mx = fmaxf(mx, __shfl_xor(mx, 2));
            float se = 0.f;
#pragma unroll
            for (int i = 0; i < 5; i++) { e[i] = __expf(v[i] - mx); se += e[i]; }
            se += __shfl_xor(se, 1);
            se += __shfl_xor(se, 2);
            const float inv = 1.f / se;
#pragma unroll
            for (int i = 0; i < 5; i++) accs[i] += e[i] * inv;
        }
        // layer-2 LIF update
#pragma unroll
        for (int r = 0; r < 4; r++) {
            const float sv = (float)((s2bits >> r) & 1u);
            const float i2 = aJ[r] + aG[r] + cc2;
            b2[r] = r2 * b2[r] + (1.f - r2) * sv;
            const float B = 0.01f + 1.8f * b2[r];
            h2m[r] = a2 * h2m[r] + (1.f - a2) * i2 - B * sv;
            const bool sp = (h2m[r] - B) > 0.f;
            s2bits = sp ? (s2bits | (1u << r)) : (s2bits & ~(1u << r));
            c2n[r] += sp ? 1.f : 0.f;
            sA2[wbase + r * 8] = sp ? ONE : (unsigned short)0;
        }
        __syncthreads();  // B2: S2 frags ready
    }

    // ---- tail: om + softmax for step 249 ----
    if (w >= 6) {
        bf16x8 f2[4];
#pragma unroll
        for (int kt = 0; kt < 4; kt++) f2[kt] = sa2v[kt * 64 + lane];
        f32x4 aO = {0.f, 0.f, 0.f, 0.f};
#pragma unroll
        for (int kt = 0; kt < 4; kt++) {
            aO = __builtin_amdgcn_mfma_f32_16x16x32_bf16(f2[kt], hO[kt], aO, 0, 0, 0);
            aO = __builtin_amdgcn_mfma_f32_16x16x32_bf16(f2[kt], lO[kt], aO, 0, 0, 0);
        }
#pragma unroll
        for (int r = 0; r < 4; r++) {
            om[r] = ao * om[r] + (1.f - ao) * (bo + aO[r]);
            if (oval) omb[(q * 4 + r) * ON + ocol] = om[r];
        }
    }
    __syncthreads();
    if (w == 0) {
        float v[5], e[5];
        float mx = -1e30f;
#pragma unroll
        for (int i = 0; i < 5; i++) { v[i] = omb[sm * ON + ob + i]; mx = fmaxf(mx, v[i]); }
        mx = fmaxf(mx, __shfl_xor(mx, 1));
        mx = fmaxf(mx, __shfl_xor(mx, 2));
        float se = 0.f;
#pragma unroll
        for (int i = 0; i < 5; i++) { e[i] = __expf(v[i] - mx); se += e[i]; }
        se += __shfl_xor(se, 1);
        se += __shfl_xor(se, 2);
        const float inv = 1.f / se;
#pragma unroll
        for (int i = 0; i < 5; i++) out[(r0 + sm) * ON + ob + i] = accs[i] + e[i] * inv;
    }
    // spike rates
#pragma unroll
    for (int r = 0; r < 4; r++) {
        out[5120 + (r0 + q * 4 + r) * HN + col] = c1[r] * (1.f / 250.f);
        out[37888 + (r0 + q * 4 + r) * HN + col] = c2n[r] * (1.f / 250.f);
    }
}

// ---------------------------------------------------------------------------
extern "C" void kernel_launch(void* const* d_in, const int* in_sizes, int n_in,
                              void* d_out, int out_size, void* d_ws, size_t ws_size,
                              hipStream_t stream) {
    const float* x        = (const float*)d_in[0];
    const float* mask     = (const float*)d_in[1];
    const float* w_ih1    = (const float*)d_in[2];
    const float* b_ih1    = (const float*)d_in[3];
    const float* w_h1h1   = (const float*)d_in[4];
    const float* b_h1h1   = (const float*)d_in[5];
    const float* w_h1h2   = (const float*)d_in[6];
    const float* b_h1h2   = (const float*)d_in[7];
    const float* w_h2h2   = (const float*)d_in[8];
    const float* b_h2h2   = (const float*)d_in[9];
    const float* w_h2o    = (const float*)d_in[10];
    const float* b_h2o    = (const float*)d_in[11];
    const float* tau_adp1 = (const float*)d_in[12];
    const float* tau_adp2 = (const float*)d_in[13];
    const float* taum1    = (const float*)d_in[14];
    const float* taum2    = (const float*)d_in[15];
    const float* taumo    = (const float*)d_in[16];
    const float* h1m0     = (const float*)d_in[17];
    const float* h2m0     = (const float*)d_in[18];
    const float* om0      = (const float*)d_in[19];
    float* out = (float*)d_out;
    float* ws  = (float*)d_ws;

    float* xin = ws + XIN_OFF;
    unsigned short* wph = (unsigned short*)(ws + WPKH_OFF);
    unsigned short* wpl = (unsigned short*)(ws + WPKL_OFF);

    packw<<<352, 256, 0, stream>>>(w_ih1, wph, wpl);
    gemm_in<<<500, 256, 0, stream>>>(x, wph, wpl, b_ih1, b_h1h1, xin);
    snn_scan<<<16, 512, 0, stream>>>(xin, mask, w_h1h1, w_h1h2, b_h1h2, w_h2h2,
                                     b_h2h2, w_h2o, b_h2o, tau_adp1, tau_adp2,
                                     taum1, taum2, taumo, h1m0, h2m0, om0, out);
}

// Round 3
// 559.061 us; speedup vs baseline: 1.1728x; 1.0906x over previous
//
#include <hip/hip_runtime.h>
#include <math.h>

#define TT 250
#define BT 256
#define HN 128
#define ON 20
#define KIN 700
#define NKT 22

// ws layout (float offsets): xin[250*256*128] | packed W hi | packed W lo
#define XIN_OFF 0
#define WPKH_OFF 8192000   // 45056 floats (90112 bf16)
#define WPKL_OFF 8237056   // 45056 floats

typedef __attribute__((ext_vector_type(8))) short bf16x8;
typedef __attribute__((ext_vector_type(4))) float f32x4;

__device__ __forceinline__ unsigned short bf16rne(float f) {
    unsigned u = __float_as_uint(f);
    unsigned r = u + 0x7fffu + ((u >> 16) & 1u);
    return (unsigned short)(r >> 16);
}
__device__ __forceinline__ void hilo(float v, short& h, short& l) {
    unsigned short hh = bf16rne(v);
    float vh = __uint_as_float((unsigned)hh << 16);
    h = (short)hh;
    l = (short)bf16rne(v - vh);
}

// async global->LDS, 16B per lane. LDS dest is wave-uniform base + lane*16;
// global src is per-lane (guide §5 / m97).
__device__ __forceinline__ void gl_lds16(const void* g, void* l) {
    __builtin_amdgcn_global_load_lds(
        (const __attribute__((address_space(1))) unsigned int*)g,
        (__attribute__((address_space(3))) unsigned int*)l, 16, 0, 0);
}

// ---------------------------------------------------------------------------
// pack w_ih1 (700x128, zero-pad K to 704) into MFMA B-frag order, hi/lo bf16.
// ---------------------------------------------------------------------------
__global__ __launch_bounds__(256) void packw(const float* __restrict__ w,
                                             unsigned short* __restrict__ ph,
                                             unsigned short* __restrict__ pl) {
    int i = blockIdx.x * 256 + threadIdx.x;   // 352*256 = 90112 = 704*128
    int k = i >> 7, c = i & 127;
    float v = (k < KIN) ? w[k * HN + c] : 0.f;
    short h, l;
    hilo(v, h, l);
    int dst = (((k >> 5) * 8 + (c >> 4)) * 64 + (((k >> 3) & 3) * 16 + (c & 15))) * 8 + (k & 7);
    ph[dst] = (unsigned short)h;
    pl[dst] = (unsigned short)l;
}

// ---------------------------------------------------------------------------
// input projection v3 (FROZEN from round 2 for attribution): 500 blocks x
// 128 rows, LDS-staged weights reused by 2 row-chunks.
// ---------------------------------------------------------------------------
__device__ __forceinline__ void stage_kt(const unsigned short* __restrict__ wph,
                                         const unsigned short* __restrict__ wpl,
                                         void* buf, int kt, int tid) {
    const char* sh = (const char*)wph + kt * 8192 + tid * 16;
    const char* sl = (const char*)wpl + kt * 8192 + tid * 16;
    char* b = (char*)buf;
    const int wb = (tid >> 6) * 1024;   // wave-uniform LDS base
    gl_lds16(sh,        b + wb);
    gl_lds16(sh + 4096, b + wb + 4096);
    gl_lds16(sl,        b + wb + 8192);
    gl_lds16(sl + 4096, b + wb + 12288);
}

__device__ __forceinline__ void loadx8(float* av, const float* p, bool tailq3) {
    *(float4*)&av[0] = *(const float4*)p;
    if (tailq3) {
        av[4] = 0.f; av[5] = 0.f; av[6] = 0.f; av[7] = 0.f;
    } else {
        *(float4*)&av[4] = *(const float4*)(p + 4);
    }
}

__global__ __launch_bounds__(256, 2) void gemm_in(const float* __restrict__ x,
        const unsigned short* __restrict__ wph, const unsigned short* __restrict__ wpl,
        const float* __restrict__ bias1, const float* __restrict__ bias2,
        float* __restrict__ xin) {
    __shared__ __align__(16) unsigned char wbuf[2][16384];   // 32 KB
    const int tid = threadIdx.x;
    const int w = tid >> 6, lane = tid & 63;
    const int q = lane >> 4, li = lane & 15;
    const long mbase = (long)blockIdx.x * 128;
    const float* xr0 = x + (mbase + w * 16 + li) * KIN + q * 8;

    f32x4 acc[2][8];
#pragma unroll
    for (int c = 0; c < 2; c++)
#pragma unroll
        for (int nt = 0; nt < 8; nt++) acc[c][nt] = (f32x4){0.f, 0.f, 0.f, 0.f};

    stage_kt(wph, wpl, wbuf[0], 0, tid);
    float av[2][8];
    loadx8(av[0], xr0, false);
    loadx8(av[1], xr0 + 64 * KIN, false);
    __syncthreads();   // drains stage(0)

    for (int kt = 0; kt < NKT; kt++) {
        if (kt + 1 < NKT)
            stage_kt(wph, wpl, wbuf[(kt + 1) & 1], kt + 1, tid);
        const bf16x8* cv = (const bf16x8*)&wbuf[kt & 1][0];
#pragma unroll
        for (int c = 0; c < 2; c++) {
            bf16x8 ah, al;
#pragma unroll
            for (int j = 0; j < 8; j++) {
                short h, l;
                hilo(av[c][j], h, l);
                ah[j] = h; al[j] = l;
            }
            if (kt + 1 < NKT)
                loadx8(av[c], xr0 + c * (64 * KIN) + (kt + 1) * 32,
                       (kt + 1 == NKT - 1) && (q == 3));
#pragma unroll
            for (int nt = 0; nt < 8; nt++) {
                bf16x8 bh = cv[nt * 64 + lane];
                bf16x8 bl = cv[512 + nt * 64 + lane];
                acc[c][nt] = __builtin_amdgcn_mfma_f32_16x16x32_bf16(ah, bh, acc[c][nt], 0, 0, 0);
                acc[c][nt] = __builtin_amdgcn_mfma_f32_16x16x32_bf16(al, bh, acc[c][nt], 0, 0, 0);
                acc[c][nt] = __builtin_amdgcn_mfma_f32_16x16x32_bf16(ah, bl, acc[c][nt], 0, 0, 0);
            }
        }
        __syncthreads();
    }

    float b12[8];
#pragma unroll
    for (int nt = 0; nt < 8; nt++) {
        int c = nt * 16 + li;
        b12[nt] = bias1[c] + bias2[c];
    }
#pragma unroll
    for (int c = 0; c < 2; c++) {
#pragma unroll
        for (int r = 0; r < 4; r++) {
            long m = mbase + c * 64 + w * 16 + q * 4 + r;
            int bq = (int)(((unsigned long long)m * 67109ull) >> 24);  // m/250, exact for m<3.2M
            int tt = (int)m - bq * 250;
            float* dst = xin + ((size_t)tt * BT + bq) * HN;
#pragma unroll
            for (int nt = 0; nt < 8; nt++) dst[nt * 16 + li] = acc[c][nt][r] + b12[nt];
        }
    }
}

// ---------------------------------------------------------------------------
// scan v8: SINGLE-BARRIER software-pipelined step. Iteration i computes:
//   LIF1(i)   from aI = S1(i-1)@W11   [g1 frags]
//   LIF2(i-1) from aJ = S1(i-1)@W12   [same g1!] + aG = S2(i-2)@W22 [f2]
//   om(i-2)   from aO = S2(i-2)@WHO   [same f2]
//   softmax(i-3) from omb parity buffer
// sA1/sA2/omb parity double-buffered; 250 barriers instead of 500; one LDS
// frag read feeds two chains; 4 independent MFMA chains issue together.
// Every f32 chain keeps its exact accumulation order -> bitwise-identical.
// ---------------------------------------------------------------------------
__global__ __launch_bounds__(512, 2) void snn_scan(
    const float* __restrict__ xin, const float* __restrict__ mask,
    const float* __restrict__ w_h1h1, const float* __restrict__ w_h1h2,
    const float* __restrict__ b_h1h2, const float* __restrict__ w_h2h2,
    const float* __restrict__ b_h2h2, const float* __restrict__ w_h2o,
    const float* __restrict__ b_h2o, const float* __restrict__ tau_adp1,
    const float* __restrict__ tau_adp2, const float* __restrict__ taum1,
    const float* __restrict__ taum2, const float* __restrict__ taumo,
    const float* __restrict__ h1m0, const float* __restrict__ h2m0,
    const float* __restrict__ om0, float* __restrict__ out) {

    __shared__ __align__(16) unsigned short sA1[2 * 2048];  // S1 frags, parity dbuf
    __shared__ __align__(16) unsigned short sA2[2 * 2048];  // S2 frags, parity dbuf
    __shared__ float omb[2][16 * ON];                       // om, parity dbuf
    __shared__ float red[8];

    const int tid = threadIdx.x;
    const int w = tid >> 6, lane = tid & 63;
    const int q = lane >> 4, li = lane & 15;
    const int col = w * 16 + li;          // this lane's neuron column
    const int r0 = blockIdx.x * 16;       // batch-row base

    // ---- weight fragments (register-resident, hi/lo bf16) ----
    bf16x8 h11[4], l11[4], h22[4], l22[4], h12[4], l12[4], hO[4], lO[4];
    const int ocol = (w == 6) ? li : 16 + li;         // WHO col (w6: 0-15, w7: 16-19)
    const bool oval = (w >= 6) && (ocol < ON);
    float pn = 0.f;
#pragma unroll
    for (int kt = 0; kt < 4; kt++) {
#pragma unroll
        for (int j = 0; j < 8; j++) {
            const int k = kt * 32 + q * 8 + j;
            const int idx = k * HN + col;
            float v11 = w_h1h1[idx] * mask[idx];
            float v22 = w_h2h2[idx] * mask[HN * HN + idx];
            float v12 = w_h1h2[idx];
            pn += fabsf(v11) + fabsf(v22);
            short hh, ll;
            hilo(v11, hh, ll); h11[kt][j] = hh; l11[kt][j] = ll;
            hilo(v22, hh, ll); h22[kt][j] = hh; l22[kt][j] = ll;
            hilo(v12, hh, ll); h12[kt][j] = hh; l12[kt][j] = ll;
            float vO = oval ? w_h2o[k * ON + ocol] : 0.f;
            hilo(vO, hh, ll); hO[kt][j] = hh; lO[kt][j] = ll;
        }
    }

    // ---- per-lane constants & state ----
    const float a1 = expf(-1.f / taum1[col]);
    const float r1 = expf(-1.f / tau_adp1[col]);
    const float a2 = expf(-1.f / taum2[col]);
    const float r2 = expf(-1.f / tau_adp2[col]);
    const float cc2 = b_h1h2[col] + b_h2h2[col];
    float h1m[4], h2m[4], b1[4], b2[4], c1[4], c2n[4];
    unsigned s1bits = 0, s2bits = 0;
#pragma unroll
    for (int r = 0; r < 4; r++) {
        h1m[r] = h1m0[(r0 + q * 4 + r) * HN + col];
        h2m[r] = h2m0[(r0 + q * 4 + r) * HN + col];
        b1[r] = 0.01f; b2[r] = 0.01f; c1[r] = 0.f; c2n[r] = 0.f;
    }
    const float ao = oval ? expf(-1.f / taumo[ocol]) : 0.f;
    const float bo = oval ? b_h2o[ocol] : 0.f;
    float om[4];
#pragma unroll
    for (int r = 0; r < 4; r++)
        om[r] = oval ? om0[(r0 + q * 4 + r) * ON + ocol] : 0.f;
    const int sm = lane >> 2, ob = (lane & 3) * 5;    // w0 softmax roles
    float accs[5] = {0.f, 0.f, 0.f, 0.f, 0.f};

    // zero spike frags (both parity buffers of sA1, sA2: 2048 u32 each array)
    {
        unsigned* z1 = (unsigned*)sA1;
        unsigned* z2 = (unsigned*)sA2;
        z1[tid] = 0u; z1[tid + 512] = 0u; z1[tid + 1024] = 0u; z1[tid + 1536] = 0u;
        z2[tid] = 0u; z2[tid + 512] = 0u; z2[tid + 1024] = 0u; z2[tid + 1536] = 0u;
    }

    // A_norm: exact f32 sum of |masked| weights, each element once
#pragma unroll
    for (int off = 32; off > 0; off >>= 1) pn += __shfl_down(pn, off);
    if (lane == 0) red[w] = pn;
    __syncthreads();
    if (tid == 0 && blockIdx.x == 0) {
        float s = 0.f;
#pragma unroll
        for (int i = 0; i < 8; i++) s += red[i];
        out[70656] = s;
    }

    // spike frag write index (this lane's 4 elements: +r*8)
    const int wbase = (w >> 1) * 512 + (((2 * w + (li >> 3)) & 3) * 16 + q * 4) * 8 + (li & 7);
    const unsigned short ONE = 0x3F80u;

    // xin running pointer: rows r0+q*4+r, col; +BT*HN per step
    const float* xp = xin + (size_t)(r0 + q * 4) * HN + col;

    for (int i = 0; i < TT; i++) {
        const int pa = i & 1;

        // xt for LIF1(i): issue VMEM earliest, consumed at the very end of body
        float xt[4];
#pragma unroll
        for (int r = 0; r < 4; r++) xt[r] = xp[r * HN];
        xp += BT * HN;

        // frag reads: g1 = S1(i-1) [buf pa^1], f2 = S2(i-2) [buf pa]
        const bf16x8* g1p = (const bf16x8*)(sA1 + ((pa ^ 1) << 11));
        const bf16x8* f2p = (const bf16x8*)(sA2 + (pa << 11));
        bf16x8 g1[4], f2[4];
#pragma unroll
        for (int kt = 0; kt < 4; kt++) {
            g1[kt] = g1p[kt * 64 + lane];
            f2[kt] = f2p[kt * 64 + lane];
        }

        // 3 (4 on w6/7) independent MFMA chains; per-chain order = v7 exactly
        f32x4 aI = {0.f, 0.f, 0.f, 0.f}, aJ = {0.f, 0.f, 0.f, 0.f}, aG = {0.f, 0.f, 0.f, 0.f};
#pragma unroll
        for (int kt = 0; kt < 4; kt++) {
            aI = __builtin_amdgcn_mfma_f32_16x16x32_bf16(g1[kt], h11[kt], aI, 0, 0, 0);
            aI = __builtin_amdgcn_mfma_f32_16x16x32_bf16(g1[kt], l11[kt], aI, 0, 0, 0);
            aJ = __builtin_amdgcn_mfma_f32_16x16x32_bf16(g1[kt], h12[kt], aJ, 0, 0, 0);
            aJ = __builtin_amdgcn_mfma_f32_16x16x32_bf16(g1[kt], l12[kt], aJ, 0, 0, 0);
            aG = __builtin_amdgcn_mfma_f32_16x16x32_bf16(f2[kt], h22[kt], aG, 0, 0, 0);
            aG = __builtin_amdgcn_mfma_f32_16x16x32_bf16(f2[kt], l22[kt], aG, 0, 0, 0);
        }
        f32x4 aO = {0.f, 0.f, 0.f, 0.f};
        if (w >= 6) {
#pragma unroll
            for (int kt = 0; kt < 4; kt++) {
                aO = __builtin_amdgcn_mfma_f32_16x16x32_bf16(f2[kt], hO[kt], aO, 0, 0, 0);
                aO = __builtin_amdgcn_mfma_f32_16x16x32_bf16(f2[kt], lO[kt], aO, 0, 0, 0);
            }
        }

        // LIF2 for step i-1 (skip at i=0; S2(-1)=0 already in zeroed buffer)
        if (i >= 1) {
            unsigned short* s2w = sA2 + ((pa ^ 1) << 11);
#pragma unroll
            for (int r = 0; r < 4; r++) {
                const float sv = (float)((s2bits >> r) & 1u);
                const float i2 = aJ[r] + aG[r] + cc2;
                b2[r] = r2 * b2[r] + (1.f - r2) * sv;
                const float B = 0.01f + 1.8f * b2[r];
                h2m[r] = a2 * h2m[r] + (1.f - a2) * i2 - B * sv;
                const bool sp = (h2m[r] - B) > 0.f;
                s2bits = sp ? (s2bits | (1u << r)) : (s2bits & ~(1u << r));
                c2n[r] += sp ? 1.f : 0.f;
                s2w[wbase + r * 8] = sp ? ONE : (unsigned short)0;
            }
        }

        // om update for step i-2 (w6/7), into parity buffer pa
        if (w >= 6 && i >= 2) {
#pragma unroll
            for (int r = 0; r < 4; r++) {
                om[r] = ao * om[r] + (1.f - ao) * (bo + aO[r]);
                if (oval) omb[pa][(q * 4 + r) * ON + ocol] = om[r];
            }
        }

        // softmax accumulate for step i-3 (w0), from parity buffer pa^1
        if (w == 0 && i >= 14) {
            float v[5], e[5];
            float mx = -1e30f;
#pragma unroll
            for (int s = 0; s < 5; s++) { v[s] = omb[pa ^ 1][sm * ON + ob + s]; mx = fmaxf(mx, v[s]); }
            mx = fmaxf(mx, __shfl_xor(mx, 1));
            mx = fmaxf(mx, __shfl_xor(mx, 2));
            float se = 0.f;
#pragma unroll
            for (int s = 0; s < 5; s++) { e[s] = __expf(v[s] - mx); se += e[s]; }
            se += __shfl_xor(se, 1);
            se += __shfl_xor(se, 2);
            const float inv = 1.f / se;
#pragma unroll
            for (int s = 0; s < 5; s++) accs[s] += e[s] * inv;
        }

        // LIF1 for step i (consumes xt last -> max VMEM latency cover)
        {
            unsigned short* s1w = sA1 + (pa << 11);
#pragma unroll
            for (int r = 0; r < 4; r++) {
                const float sv = (float)((s1bits >> r) & 1u);
                const float i1 = xt[r] + aI[r];       // biases folded into xin
                b1[r] = r1 * b1[r] + (1.f - r1) * sv;
                const float B = 0.01f + 1.8f * b1[r];
                h1m[r] = a1 * h1m[r] + (1.f - a1) * i1 - B * sv;
                const bool sp = (h1m[r] - B) > 0.f;
                s1bits = sp ? (s1bits | (1u << r)) : (s1bits & ~(1u << r));
                c1[r] += sp ? 1.f : 0.f;
                s1w[wbase + r * 8] = sp ? ONE : (unsigned short)0;
            }
        }
        __syncthreads();   // single barrier: publishes S1(i), S2(i-1), om(i-2)
    }

    // ================= epilogue =================
    // E1 (i=250): LIF2(249), om(248), softmax(247)
    {
        const bf16x8* g1p = (const bf16x8*)(sA1 + 2048);  // S1(249)
        const bf16x8* f2p = (const bf16x8*)(sA2);         // S2(248)
        bf16x8 g1[4], f2[4];
#pragma unroll
        for (int kt = 0; kt < 4; kt++) {
            g1[kt] = g1p[kt * 64 + lane];
            f2[kt] = f2p[kt * 64 + lane];
        }
        f32x4 aJ = {0.f, 0.f, 0.f, 0.f}, aG = {0.f, 0.f, 0.f, 0.f};
#pragma unroll
        for (int kt = 0; kt < 4; kt++) {
            aJ = __builtin_amdgcn_mfma_f32_16x16x32_bf16(g1[kt], h12[kt], aJ, 0, 0, 0);
            aJ = __builtin_amdgcn_mfma_f32_16x16x32_bf16(g1[kt], l12[kt], aJ, 0, 0, 0);
            aG = __builtin_amdgcn_mfma_f32_16x16x32_bf16(f2[kt], h22[kt], aG, 0, 0, 0);
            aG = __builtin_amdgcn_mfma_f32_16x16x32_bf16(f2[kt], l22[kt], aG, 0, 0, 0);
        }
        f32x4 aO = {0.f, 0.f, 0.f, 0.f};
        if (w >= 6) {
#pragma unroll
            for (int kt = 0; kt < 4; kt++) {
                aO = __builtin_amdgcn_mfma_f32_16x16x32_bf16(f2[kt], hO[kt], aO, 0, 0, 0);
                aO = __builtin_amdgcn_mfma_f32_16x16x32_bf16(f2[kt], lO[kt], aO, 0, 0, 0);
            }
        }
        // LIF2 step 249 -> sA2 buf1
        {
            unsigned short* s2w = sA2 + 2048;
#pragma unroll
            for (int r = 0; r < 4; r++) {
                const float sv = (float)((s2bits >> r) & 1u);
                const float i2 = aJ[r] + aG[r] + cc2;
                b2[r] = r2 * b2[r] + (1.f - r2) * sv;
                const float B = 0.01f + 1.8f * b2[r];
                h2m[r] = a2 * h2m[r] + (1.f - a2) * i2 - B * sv;
                const bool sp = (h2m[r] - B) > 0.f;
                s2bits = sp ? (s2bits | (1u << r)) : (s2bits & ~(1u << r));
                c2n[r] += sp ? 1.f : 0.f;
                s2w[wbase + r * 8] = sp ? ONE : (unsigned short)0;
            }
        }
        if (w >= 6) {   // om(248) -> omb[0]
#pragma unroll
            for (int r = 0; r < 4; r++) {
                om[r] = ao * om[r] + (1.f - ao) * (bo + aO[r]);
                if (oval) omb[0][(q * 4 + r) * ON + ocol] = om[r];
            }
        }
        if (w == 0) {   // softmax step 247 from omb[1]
            float v[5], e[5];
            float mx = -1e30f;
#pragma unroll
            for (int s = 0; s < 5; s++) { v[s] = omb[1][sm * ON + ob + s]; mx = fmaxf(mx, v[s]); }
            mx = fmaxf(mx, __shfl_xor(mx, 1));
            mx = fmaxf(mx, __shfl_xor(mx, 2));
            float se = 0.f;
#pragma unroll
            for (int s = 0; s < 5; s++) { e[s] = __expf(v[s] - mx); se += e[s]; }
            se += __shfl_xor(se, 1);
            se += __shfl_xor(se, 2);
            const float inv = 1.f / se;
#pragma unroll
            for (int s = 0; s < 5; s++) accs[s] += e[s] * inv;
        }
        __syncthreads();
    }
    // E2 (i=251): om(249), softmax(248)
    {
        if (w >= 6) {
            const bf16x8* f2p = (const bf16x8*)(sA2 + 2048);  // S2(249)
            bf16x8 f2[4];
#pragma unroll
            for (int kt = 0; kt < 4; kt++) f2[kt] = f2p[kt * 64 + lane];
            f32x4 aO = {0.f, 0.f, 0.f, 0.f};
#pragma unroll
            for (int kt = 0; kt < 4; kt++) {
                aO = __builtin_amdgcn_mfma_f32_16x16x32_bf16(f2[kt], hO[kt], aO, 0, 0, 0);
                aO = __builtin_amdgcn_mfma_f32_16x16x32_bf16(f2[kt], lO[kt], aO, 0, 0, 0);
            }
#pragma unroll
            for (int r = 0; r < 4; r++) {
                om[r] = ao * om[r] + (1.f - ao) * (bo + aO[r]);
                if (oval) omb[1][(q * 4 + r) * ON + ocol] = om[r];
            }
        }
        if (w == 0) {   // softmax step 248 from omb[0]
            float v[5], e[5];
            float mx = -1e30f;
#pragma unroll
            for (int s = 0; s < 5; s++) { v[s] = omb[0][sm * ON + ob + s]; mx = fmaxf(mx, v[s]); }
            mx = fmaxf(mx, __shfl_xor(mx, 1));
            mx = fmaxf(mx, __shfl_xor(mx, 2));
            float se = 0.f;
#pragma unroll
            for (int s = 0; s < 5; s++) { e[s] = __expf(v[s] - mx); se += e[s]; }
            se += __shfl_xor(se, 1);
            se += __shfl_xor(se, 2);
            const float inv = 1.f / se;
#pragma unroll
            for (int s = 0; s < 5; s++) accs[s] += e[s] * inv;
        }
        __syncthreads();
    }
    // E3: softmax(249) from omb[1], fused into output write
    if (w == 0) {
        float v[5], e[5];
        float mx = -1e30f;
#pragma unroll
        for (int s = 0; s < 5; s++) { v[s] = omb[1][sm * ON + ob + s]; mx = fmaxf(mx, v[s]); }
        mx = fmaxf(mx, __shfl_xor(mx, 1));
        mx = fmaxf(mx, __shfl_xor(mx, 2));
        float se = 0.f;
#pragma unroll
        for (int s = 0; s < 5; s++) { e[s] = __expf(v[s] - mx); se += e[s]; }
        se += __shfl_xor(se, 1);
        se += __shfl_xor(se, 2);
        const float inv = 1.f / se;
#pragma unroll
        for (int s = 0; s < 5; s++) out[(r0 + sm) * ON + ob + s] = accs[s] + e[s] * inv;
    }
    // spike rates
#pragma unroll
    for (int r = 0; r < 4; r++) {
        out[5120 + (r0 + q * 4 + r) * HN + col] = c1[r] * (1.f / 250.f);
        out[37888 + (r0 + q * 4 + r) * HN + col] = c2n[r] * (1.f / 250.f);
    }
}

// ---------------------------------------------------------------------------
extern "C" void kernel_launch(void* const* d_in, const int* in_sizes, int n_in,
                              void* d_out, int out_size, void* d_ws, size_t ws_size,
                              hipStream_t stream) {
    const float* x        = (const float*)d_in[0];
    const float* mask     = (const float*)d_in[1];
    const float* w_ih1    = (const float*)d_in[2];
    const float* b_ih1    = (const float*)d_in[3];
    const float* w_h1h1   = (const float*)d_in[4];
    const float* b_h1h1   = (const float*)d_in[5];
    const float* w_h1h2   = (const float*)d_in[6];
    const float* b_h1h2   = (const float*)d_in[7];
    const float* w_h2h2   = (const float*)d_in[8];
    const float* b_h2h2   = (const float*)d_in[9];
    const float* w_h2o    = (const float*)d_in[10];
    const float* b_h2o    = (const float*)d_in[11];
    const float* tau_adp1 = (const float*)d_in[12];
    const float* tau_adp2 = (const float*)d_in[13];
    const float* taum1    = (const float*)d_in[14];
    const float* taum2    = (const float*)d_in[15];
    const float* taumo    = (const float*)d_in[16];
    const float* h1m0     = (const float*)d_in[17];
    const float* h2m0     = (const float*)d_in[18];
    const float* om0      = (const float*)d_in[19];
    float* out = (float*)d_out;
    float* ws  = (float*)d_ws;

    float* xin = ws + XIN_OFF;
    unsigned short* wph = (unsigned short*)(ws + WPKH_OFF);
    unsigned short* wpl = (unsigned short*)(ws + WPKL_OFF);

    packw<<<352, 256, 0, stream>>>(w_ih1, wph, wpl);
    gemm_in<<<500, 256, 0, stream>>>(x, wph, wpl, b_ih1, b_h1h1, xin);
    snn_scan<<<16, 512, 0, stream>>>(xin, mask, w_h1h1, w_h1h2, b_h1h2, w_h2h2,
                                     b_h2h2, w_h2o, b_h2o, tau_adp1, tau_adp2,
                                     taum1, taum2, taumo, h1m0, h2m0, om0, out);
}